// Round 10
// baseline (17.661 us; speedup 1.0000x reference)
//
#include <hip/hip_runtime.h>

// Polyphase resampler 16000 -> 14400 Hz (SpeedPerturb).
// stride 10, P = 9 phases, W = 14 taps.
// Wave-decoupled, DMA-staged, 2-span software pipeline:
//   wave owns spans s0=2*pr, s0+1 (span = 64 periods = 576 outputs).
//   Issue 3+3 UNCONDITIONAL global_load_lds (768 floats/span, issue order
//   pinned with sched_barrier(0)) -> vmcnt(3) -> compute span0 -> store ->
//   vmcnt(3) (3 stores stay in flight; span1 loads landed under span0
//   compute) -> compute span1 -> store. Windows read as 12x ds_read_b64,
//   float2-unit lane-stride 5 (gcd(5,16)=1 -> b64 floor, conflict-free).
//   No __syncthreads anywhere. Edge waves (pr==0, pr==374) use guarded
//   direct loads.

#define RS_TPB 256
#define WPR 375      // wave-pairs per batch row (750 spans/row)
#define SPAN_F 768   // floats staged per span (3 x 64 lanes x 4 floats)

typedef __attribute__((address_space(1))) const void gvoid_t;
typedef __attribute__((address_space(3))) void lvoid_t;

__device__ __forceinline__ void fma_store(const float* win, float* sout,
                                          const float* __restrict__ wgt,
                                          float* __restrict__ orow, int lane) {
  const int OFF[9] = {0, 1, 2, 3, 4, 5, 6, 8, 9};
#pragma unroll
  for (int j = 0; j < 9; ++j) {
    float acc = 0.0f;
#pragma unroll
    for (int t = 0; t < 14; ++t)
      acc = fmaf(win[OFF[j] + t], wgt[14 * j + t], acc);
    sout[lane * 9 + j] = acc;  // stride-9 b32: gcd(9,32)=1 -> conflict-free
  }
  __builtin_amdgcn_wave_barrier();
#pragma unroll
  for (int it = 0; it < 3; ++it) {
    const int i4 = it * 64 + lane;
    if (i4 < 144) {
      const float4 v = *reinterpret_cast<const float4*>(&sout[i4 << 2]);
      *reinterpret_cast<float4*>(orow + (i4 << 2)) = v;
    }
  }
  __builtin_amdgcn_wave_barrier();
}

__device__ __forceinline__ void compute_span_lds(const float* sin_buf,
                                                 float* sout,
                                                 const float* __restrict__ wgt,
                                                 float* __restrict__ orow,
                                                 int lane) {
  float win[24];
  const float2* s2 = reinterpret_cast<const float2*>(sin_buf);
  const int d0 = 5 * lane + 5;  // window floats [10*lane+10, 10*lane+34)
#pragma unroll
  for (int r = 0; r < 12; ++r) {
    const float2 v = s2[d0 + r];
    win[2 * r] = v.x;
    win[2 * r + 1] = v.y;
  }
  fma_store(win, sout, wgt, orow, lane);
}

__device__ __forceinline__ void compute_span_direct(
    int s, int lane, const float* __restrict__ wrow, int N, float* sout,
    const float* __restrict__ wgt, float* __restrict__ orow) {
  const int gbase = 640 * s + 10 * lane - 6;
  float win[24];
#pragma unroll
  for (int i = 0; i < 24; ++i) {
    const int gi = gbase + i;
    win[i] = (gi >= 0 && gi < N) ? wrow[gi] : 0.0f;
  }
  fma_store(win, sout, wgt, orow, lane);
}

__global__ __launch_bounds__(RS_TPB) void resample_kernel(
    const float* __restrict__ wav, const float* __restrict__ wgt,
    float* __restrict__ out, int N, int TOT) {
  __shared__ __align__(16) float s_in[4][2][SPAN_F];  // 24576 B
  __shared__ __align__(16) float s_out[4][576];       //  9216 B

  const int tid = threadIdx.x;
  const int w = tid >> 6;
  const int lane = tid & 63;
  const int gw = blockIdx.x * 4 + w;
  const unsigned bu = (unsigned)gw / WPR;
  const int pr = gw - (int)bu * WPR;
  const int s0 = 2 * pr;

  const float* __restrict__ wrow = wav + (size_t)bu * N;
  float* __restrict__ obase = out + (size_t)bu * (size_t)TOT;
  float* sout = &s_out[w][0];

  if (pr > 0 && pr < WPR - 1) {
    const int a0 = 640 * s0 - 16;  // 16B-aligned; pr>=1 -> a0 >= 1264
    const int a1 = a0 + 640;       // a1 + 768 <= 478832 <= N for pr <= 373
    float* b0 = &s_in[w][0][0];
    float* b1 = &s_in[w][1][0];
    // --- span 0 loads (issue group 0) ---
#pragma unroll
    for (int it = 0; it < 3; ++it)
      __builtin_amdgcn_global_load_lds(
          (gvoid_t*)(wrow + a0 + it * 256 + lane * 4),
          (lvoid_t*)(b0 + it * 256), 16, 0, 0);
    __builtin_amdgcn_sched_barrier(0);
    // --- span 1 loads (issue group 1) ---
#pragma unroll
    for (int it = 0; it < 3; ++it)
      __builtin_amdgcn_global_load_lds(
          (gvoid_t*)(wrow + a1 + it * 256 + lane * 4),
          (lvoid_t*)(b1 + it * 256), 16, 0, 0);
    __builtin_amdgcn_sched_barrier(0);
    // 6 outstanding; wait the 3 oldest (span 0), keep span 1 in flight.
    asm volatile("s_waitcnt vmcnt(3)" ::: "memory");
    __builtin_amdgcn_sched_barrier(0);
    compute_span_lds(b0, sout, wgt, obase + (size_t)s0 * 576, lane);
    // outstanding: 3 span-1 loads (oldest) + 3 output stores (newest).
    asm volatile("s_waitcnt vmcnt(3)" ::: "memory");
    __builtin_amdgcn_sched_barrier(0);
    compute_span_lds(b1, sout, wgt, obase + (size_t)(s0 + 1) * 576, lane);
  } else {
    compute_span_direct(s0, lane, wrow, N, sout, wgt,
                        obase + (size_t)s0 * 576);
    compute_span_direct(s0 + 1, lane, wrow, N, sout, wgt,
                        obase + (size_t)(s0 + 1) * 576);
  }
}

extern "C" void kernel_launch(void* const* d_in, const int* in_sizes, int n_in,
                              void* d_out, int out_size, void* d_ws, size_t ws_size,
                              hipStream_t stream) {
  const float* wav = (const float*)d_in[0];
  const float* wgt = (const float*)d_in[1];
  float* out = (float*)d_out;

  const int N = 480000;
  const int B = in_sizes[0] / N;   // 16
  const int TOT = out_size / B;    // 432000 = 750 spans * 576
  const int n_waves = B * WPR;     // 6000
  dim3 grid(n_waves / 4);          // 1500 blocks of 4 independent waves

  resample_kernel<<<grid, RS_TPB, 0, stream>>>(wav, wgt, out, N, TOT);
}

// Round 11
// 15.569 us; speedup vs baseline: 1.1343x; 1.1343x over previous
//
#include <hip/hip_runtime.h>

// Polyphase resampler 16000 -> 14400 Hz (SpeedPerturb).
// stride 10, P = 9 phases, W = 14 taps.
// R8 backbone (max-TLP, wave-decoupled, direct loads) with the window
// fetched as 6 UNALIGNED float4 (dword-aligned is sufficient on gfx950)
// instead of 12 float2 -> halves per-wave L1 line-touches.
// Wave owns 64 periods m (outputs 9m..9m+8). out[9m+j] =
// sum_w wav[10m-6+OFF[j]+w]*wgt[14j+w], OFF={0,1,2,3,4,5,6,8,9}.
// M % 64 == 0, TOT == 9*M exactly -> no tails.

#define RS_TPB 256

typedef float float4u __attribute__((ext_vector_type(4), aligned(4)));

__global__ __launch_bounds__(RS_TPB) void resample_kernel(
    const float* __restrict__ wav, const float* __restrict__ wgt,
    float* __restrict__ out, int N, int M, int TOT) {
  __shared__ __align__(16) float s_out[4][576];   // per-wave 2304 B

  const int b = blockIdx.y;
  const int tid = threadIdx.x;
  const int w = tid >> 6;
  const int lane = tid & 63;
  const int wbase = blockIdx.x * RS_TPB + (w << 6);  // first period of wave
  if (wbase >= M) return;            // wave-uniform; no block barrier exists

  const int m = wbase + lane;
  const float* __restrict__ wrow = wav + (size_t)b * N;

  // Window: wav[10m-6 .. 10m+17] (24 floats), dword-aligned (in fact 8B).
  const int gbase = 10 * m - 6;
  float win[24];
  if (gbase >= 0 && gbase + 24 <= N) {
#pragma unroll
    for (int r = 0; r < 6; ++r) {
      const float4u v = *reinterpret_cast<const float4u*>(wrow + gbase + 4 * r);
      win[4 * r + 0] = v.x;
      win[4 * r + 1] = v.y;
      win[4 * r + 2] = v.z;
      win[4 * r + 3] = v.w;
    }
  } else {
#pragma unroll
    for (int i = 0; i < 24; ++i) {
      const int gi = gbase + i;
      win[i] = (gi >= 0 && gi < N) ? wrow[gi] : 0.0f;
    }
  }

  const int OFF[9] = {0, 1, 2, 3, 4, 5, 6, 8, 9};
#pragma unroll
  for (int j = 0; j < 9; ++j) {
    const float* wp = &wgt[14 * j];
    float acc = 0.0f;
#pragma unroll
    for (int t = 0; t < 14; ++t) acc = fmaf(win[OFF[j] + t], wp[t], acc);
    s_out[w][lane * 9 + j] = acc;   // stride-9 b32: gcd(9,32)=1 -> conflict-free
  }
  __builtin_amdgcn_wave_barrier();  // same-wave order; lgkmcnt by compiler

  // Coalesced float4 store of this wave's 576 contiguous outputs.
  float* __restrict__ orow = out + (size_t)b * TOT + (size_t)wbase * 9;
  const float4* so4 = reinterpret_cast<const float4*>(&s_out[w][0]);
#pragma unroll
  for (int it = 0; it < 3; ++it) {
    const int i4 = it * 64 + lane;
    if (i4 < 144) *reinterpret_cast<float4*>(orow + (i4 << 2)) = so4[i4];
  }
}

extern "C" void kernel_launch(void* const* d_in, const int* in_sizes, int n_in,
                              void* d_out, int out_size, void* d_ws, size_t ws_size,
                              hipStream_t stream) {
  const float* wav = (const float*)d_in[0];
  const float* wgt = (const float*)d_in[1];
  float* out = (float*)d_out;

  const int N = 480000;
  const int B = in_sizes[0] / N;   // 16
  const int TOT = out_size / B;    // 432000
  const int M = (TOT + 8) / 9;     // 48000 periods (multiple of 64)

  dim3 grid((M + RS_TPB - 1) / RS_TPB, B);
  resample_kernel<<<grid, RS_TPB, 0, stream>>>(wav, wgt, out, N, M, TOT);
}

// Round 13
// 14.363 us; speedup vs baseline: 1.2296x; 1.0840x over previous
//
#include <hip/hip_runtime.h>

// Polyphase resampler 16000 -> 14400 Hz (SpeedPerturb).
// stride 10, P = 9 phases, W = 14 taps.
// R11 backbone (max-TLP, wave-decoupled, 6 unaligned-float4 direct loads)
// + NONTEMPORAL output stores (nt: no L2 write-allocate; output is never
// re-read in-kernel, so the write stream stops competing with reads in TCC).
// Wave owns 64 periods m (outputs 9m..9m+8). out[9m+j] =
// sum_w wav[10m-6+OFF[j]+w]*wgt[14j+w], OFF={0,1,2,3,4,5,6,8,9}.
// M % 64 == 0, TOT == 9*M exactly -> no tails.

#define RS_TPB 256

typedef float float4u __attribute__((ext_vector_type(4), aligned(4)));
typedef float vfloat4 __attribute__((ext_vector_type(4)));  // 16B-aligned native

__global__ __launch_bounds__(RS_TPB) void resample_kernel(
    const float* __restrict__ wav, const float* __restrict__ wgt,
    float* __restrict__ out, int N, int M, int TOT) {
  __shared__ __align__(16) float s_out[4][576];   // per-wave 2304 B

  const int b = blockIdx.y;
  const int tid = threadIdx.x;
  const int w = tid >> 6;
  const int lane = tid & 63;
  const int wbase = blockIdx.x * RS_TPB + (w << 6);  // first period of wave
  if (wbase >= M) return;            // wave-uniform; no block barrier exists

  const int m = wbase + lane;
  const float* __restrict__ wrow = wav + (size_t)b * N;

  // Window: wav[10m-6 .. 10m+17] (24 floats), dword-aligned (in fact 8B).
  const int gbase = 10 * m - 6;
  float win[24];
  if (gbase >= 0 && gbase + 24 <= N) {
#pragma unroll
    for (int r = 0; r < 6; ++r) {
      const float4u v = *reinterpret_cast<const float4u*>(wrow + gbase + 4 * r);
      win[4 * r + 0] = v.x;
      win[4 * r + 1] = v.y;
      win[4 * r + 2] = v.z;
      win[4 * r + 3] = v.w;
    }
  } else {
#pragma unroll
    for (int i = 0; i < 24; ++i) {
      const int gi = gbase + i;
      win[i] = (gi >= 0 && gi < N) ? wrow[gi] : 0.0f;
    }
  }

  const int OFF[9] = {0, 1, 2, 3, 4, 5, 6, 8, 9};
#pragma unroll
  for (int j = 0; j < 9; ++j) {
    const float* wp = &wgt[14 * j];
    float acc = 0.0f;
#pragma unroll
    for (int t = 0; t < 14; ++t) acc = fmaf(win[OFF[j] + t], wp[t], acc);
    s_out[w][lane * 9 + j] = acc;   // stride-9 b32: gcd(9,32)=1 -> conflict-free
  }
  __builtin_amdgcn_wave_barrier();  // same-wave order; lgkmcnt by compiler

  // Coalesced NONTEMPORAL float4 store of this wave's 576 contiguous outputs.
  float* __restrict__ orow = out + (size_t)b * TOT + (size_t)wbase * 9;
  const vfloat4* so4 = reinterpret_cast<const vfloat4*>(&s_out[w][0]);
#pragma unroll
  for (int it = 0; it < 3; ++it) {
    const int i4 = it * 64 + lane;
    if (i4 < 144)
      __builtin_nontemporal_store(so4[i4],
                                  reinterpret_cast<vfloat4*>(orow + (i4 << 2)));
  }
}

extern "C" void kernel_launch(void* const* d_in, const int* in_sizes, int n_in,
                              void* d_out, int out_size, void* d_ws, size_t ws_size,
                              hipStream_t stream) {
  const float* wav = (const float*)d_in[0];
  const float* wgt = (const float*)d_in[1];
  float* out = (float*)d_out;

  const int N = 480000;
  const int B = in_sizes[0] / N;   // 16
  const int TOT = out_size / B;    // 432000
  const int M = (TOT + 8) / 9;     // 48000 periods (multiple of 64)

  dim3 grid((M + RS_TPB - 1) / RS_TPB, B);
  resample_kernel<<<grid, RS_TPB, 0, stream>>>(wav, wgt, out, N, M, TOT);
}